// Round 1
// baseline (1882.145 us; speedup 1.0000x reference)
//
#include <hip/hip_runtime.h>
#include <stdint.h>

#define NN 50000
#define EE 400000
#define TT 7
#define LN_EPS 1e-5f

__device__ __forceinline__ float leaky01(float x){ return x > 0.f ? x : 0.01f*x; }
__device__ __forceinline__ float sigmoidf(float x){ return 1.f/(1.f+__expf(-x)); }
__device__ __forceinline__ float tanhfast(float x){ float e=__expf(2.f*x); return 1.f - 2.f/(e+1.f); }
__device__ __forceinline__ unsigned bf16rne(float f){
  unsigned u = __float_as_uint(f);
  return (u + 0x7fffu + ((u>>16)&1u)) >> 16;
}
__device__ __forceinline__ float blo(unsigned u){ return __uint_as_float(u<<16); }
__device__ __forceinline__ float bhi(unsigned u){ return __uint_as_float(u & 0xffff0000u); }

// ---------------- graph norm / CSR build ----------------
__global__ void k_init_deg(float* deg){
  int i = blockIdx.x*blockDim.x + threadIdx.x;
  if (i < NN) deg[i] = 1.0f;                // self-loop weight
}
__global__ void k_edge_count(const int* __restrict__ src, const int* __restrict__ dst,
                             const float* __restrict__ ew, float* deg, int* counts){
  int e = blockIdx.x*blockDim.x + threadIdx.x;
  if (e < EE){
    int d = dst[e];
    atomicAdd(&deg[d], ew[e]);
    atomicAdd(&counts[d], 1);
  }
}
__global__ void k_dinv(float* deg){
  int i = blockIdx.x*blockDim.x + threadIdx.x;
  if (i < NN) deg[i] = rsqrtf(deg[i]);      // deg >= 1 always
}
// single-block inclusive scan over counts -> rowptr/cursor
__global__ void k_scan(const int* __restrict__ counts, int* rowptr, int* cursor){
  __shared__ int sb[2][1024];
  int tid = threadIdx.x;
  int carry = 0;
  for (int base = 0; base < NN; base += 1024){
    int i = base + tid;
    int v = (i < NN) ? counts[i] : 0;
    int cur = 0;
    sb[0][tid] = v;
    __syncthreads();
    for (int off = 1; off < 1024; off <<= 1){
      int val = sb[cur][tid];
      if (tid >= off) val += sb[cur][tid - off];
      sb[cur^1][tid] = val;
      cur ^= 1;
      __syncthreads();
    }
    int incl = sb[cur][tid];
    if (i < NN){ rowptr[i+1] = carry + incl; cursor[i] = carry + incl - v; }
    int tot = sb[cur][1023];
    __syncthreads();
    carry += tot;
  }
  if (tid == 0) rowptr[0] = 0;
}
__global__ void k_scatter(const int* __restrict__ src, const int* __restrict__ dst,
                          const float* __restrict__ ew, const float* __restrict__ dinv,
                          int* cursor, int* colsrc, float* enorm){
  int e = blockIdx.x*blockDim.x + threadIdx.x;
  if (e < EE){
    int s = src[e], d = dst[e];
    float nv = dinv[s]*ew[e]*dinv[d];
    int slot = atomicAdd(&cursor[d], 1);
    colsrc[slot] = s;
    enorm[slot] = nv;
  }
}

// ---------------- LSTM weight packing ----------------
// WB[k*64+g] = uint4 of 8 bf16: (Wih gates i,f,g,o)[*,g][k], (Whh gates)[*,g][k]
__global__ void k_prep_lstm(const float* __restrict__ Wih0, const float* __restrict__ Whh0,
                            const float* __restrict__ Wih1, const float* __restrict__ Whh1,
                            uint4* WB){
  int idx = blockIdx.x*blockDim.x + threadIdx.x;
  if (idx >= 2*4096) return;
  int L = idx >> 12;
  int r = idx & 4095;
  int k = r >> 6, g = r & 63;
  const float* Wih = L ? Wih1 : Wih0;
  const float* Whh = L ? Whh1 : Whh0;
  uint4 v;
  v.x = bf16rne(Wih[(0*64+g)*64+k]) | (bf16rne(Wih[(1*64+g)*64+k])<<16);
  v.y = bf16rne(Wih[(2*64+g)*64+k]) | (bf16rne(Wih[(3*64+g)*64+k])<<16);
  v.z = bf16rne(Whh[(0*64+g)*64+k]) | (bf16rne(Whh[(1*64+g)*64+k])<<16);
  v.w = bf16rne(Whh[(2*64+g)*64+k]) | (bf16rne(Whh[(3*64+g)*64+k])<<16);
  WB[L*4096 + k*64 + g] = v;
}
__global__ void k_prep_bias(const float* bih0, const float* bhh0,
                            const float* bih1, const float* bhh1, float* BS){
  int j = threadIdx.x; int L = blockIdx.x;
  if (j < 256) BS[L*256+j] = L ? (bih1[j]+bhh1[j]) : (bih0[j]+bhh0[j]);
}

// ---------------- GCN ----------------
// AX[i][0..48] = sum over in-edges (+self) of norm * x[src][0..48]; one wave per node
__global__ __launch_bounds__(256) void k_agg_x(const float* __restrict__ x,
        const float* __restrict__ dinv, const int* __restrict__ rowptr,
        const int* __restrict__ colsrc, const float* __restrict__ enorm,
        float* __restrict__ AX){
  int lane = threadIdx.x & 63, w = threadIdx.x >> 6;
  int i = blockIdx.x*4 + w;
  int beg = rowptr[i], end = rowptr[i+1];
  float di = dinv[i];
  float acc = 0.f;
  if (lane < 49) acc = di*di*x[(size_t)i*49 + lane];
  for (int s = beg; s < end; ++s){
    int cs = colsrc[s]; float wv = enorm[s];
    if (lane < 49) acc += wv * x[(size_t)cs*49 + lane];
  }
  if (lane < 49) AX[(size_t)i*49 + lane] = acc;
}
// H1 = leaky(AX_t @ Wg1 + bg1)
__global__ __launch_bounds__(256) void k_y1(const float* __restrict__ AX,
        const float* __restrict__ Wg1, const float* __restrict__ bg1,
        float* __restrict__ H1, int t){
  __shared__ float sw[7*64];
  __shared__ float sb[64];
  int tid = threadIdx.x;
  for (int i = tid; i < 448; i += 256) sw[i] = Wg1[i];
  if (tid < 64) sb[tid] = bg1[tid];
  __syncthreads();
  int c = tid & 63, w = tid >> 6;
  int n = blockIdx.x*4 + w;
  const float* ax = AX + (size_t)n*49 + t*7;
  float acc = sb[c];
  #pragma unroll
  for (int k = 0; k < 7; ++k) acc += ax[k]*sw[k*64+c];
  H1[(size_t)n*64+c] = leaky01(acc);
}
// Z2 = H1 @ Wg2 (no bias; added post-aggregation), 16 nodes/block, 4 nodes/thread
__global__ __launch_bounds__(256) void k_z2(const float* __restrict__ H1,
        const float* __restrict__ Wg2, float* __restrict__ Z2){
  __shared__ float sw[64*64];
  __shared__ __align__(16) float sr[16*64];
  int tid = threadIdx.x;
  const float4* w4 = (const float4*)Wg2;
  float4* sw4 = (float4*)sw;
  #pragma unroll
  for (int i = 0; i < 4; ++i) sw4[tid + i*256] = w4[tid + i*256];
  int base = blockIdx.x*16;
  ((float4*)sr)[tid] = ((const float4*)(H1 + (size_t)base*64))[tid];
  __syncthreads();
  int c = tid & 63, w = tid >> 6;
  float a0=0.f, a1=0.f, a2=0.f, a3=0.f;
  const float* r = sr + w*256;
  for (int k = 0; k < 64; ++k){
    float wv = sw[k*64+c];
    a0 += r[k]*wv; a1 += r[64+k]*wv; a2 += r[128+k]*wv; a3 += r[192+k]*wv;
  }
  size_t o = (size_t)(base + w*4)*64 + c;
  Z2[o] = a0; Z2[o+64] = a1; Z2[o+128] = a2; Z2[o+192] = a3;
}
// XT = LN(leaky(A@Z2 + bg2)) ; one wave per node, lane = feature
__global__ __launch_bounds__(256) void k_agg_ln(const float* __restrict__ Z2,
        const float* __restrict__ dinv, const int* __restrict__ rowptr,
        const int* __restrict__ colsrc, const float* __restrict__ enorm,
        const float* __restrict__ bg2, const float* __restrict__ lng,
        const float* __restrict__ lnb, float* __restrict__ XT){
  int lane = threadIdx.x & 63, w = threadIdx.x >> 6;
  int i = blockIdx.x*4 + w;
  int beg = rowptr[i], end = rowptr[i+1];
  float di = dinv[i];
  float acc = di*di*Z2[(size_t)i*64 + lane];
  for (int s = beg; s < end; ++s){
    acc += enorm[s]*Z2[(size_t)colsrc[s]*64 + lane];
  }
  acc += bg2[lane];
  acc = leaky01(acc);
  float sum = acc;
  #pragma unroll
  for (int off = 32; off >= 1; off >>= 1) sum += __shfl_xor(sum, off, 64);
  float mu = sum * (1.f/64.f);
  float d = acc - mu;
  float vs = d*d;
  #pragma unroll
  for (int off = 32; off >= 1; off >>= 1) vs += __shfl_xor(vs, off, 64);
  float rs = rsqrtf(vs*(1.f/64.f) + LN_EPS);
  XT[(size_t)i*64+lane] = d*rs*lng[lane] + lnb[lane];
}

// ---------------- LSTM step (one layer), in-place h/c update ----------------
// 16 nodes/block; thread (w,g) computes gates i,f,g,o for unit g of 4 nodes.
__global__ __launch_bounds__(256) void k_lstm(const float* __restrict__ xin,
        float* __restrict__ h, float* __restrict__ c,
        const uint4* __restrict__ WB, const float* __restrict__ BS){
  __shared__ __align__(16) float sx[16*64];
  __shared__ __align__(16) float sh[16*64];
  int tid = threadIdx.x;
  int base = blockIdx.x*16;
  ((float4*)sx)[tid] = ((const float4*)(xin + (size_t)base*64))[tid];
  ((float4*)sh)[tid] = ((const float4*)(h   + (size_t)base*64))[tid];
  __syncthreads();
  int g = tid & 63, w = tid >> 6;
  float b0=BS[g], b1=BS[64+g], b2=BS[128+g], b3=BS[192+g];
  float acc[4][4];
  #pragma unroll
  for (int j = 0; j < 4; ++j){ acc[j][0]=b0; acc[j][1]=b1; acc[j][2]=b2; acc[j][3]=b3; }
  const float* px = sx + w*256;
  const float* ph = sh + w*256;
  #pragma unroll 8
  for (int k = 0; k < 64; ++k){
    uint4 wv = WB[k*64+g];
    float wi0=blo(wv.x), wi1=bhi(wv.x), wi2=blo(wv.y), wi3=bhi(wv.y);
    float wh0=blo(wv.z), wh1=bhi(wv.z), wh2=blo(wv.w), wh3=bhi(wv.w);
    #pragma unroll
    for (int j = 0; j < 4; ++j){
      float xv = px[j*64+k], hv = ph[j*64+k];
      acc[j][0] += xv*wi0 + hv*wh0;
      acc[j][1] += xv*wi1 + hv*wh1;
      acc[j][2] += xv*wi2 + hv*wh2;
      acc[j][3] += xv*wi3 + hv*wh3;
    }
  }
  #pragma unroll
  for (int j = 0; j < 4; ++j){
    size_t idx = (size_t)(base + w*4 + j)*64 + g;
    float ci = c[idx];
    float ig = sigmoidf(acc[j][0]);
    float fg = sigmoidf(acc[j][1]);
    float gg = tanhfast(acc[j][2]);
    float og = sigmoidf(acc[j][3]);
    float cn = fg*ci + ig*gg;
    c[idx] = cn;
    h[idx] = og*tanhfast(cn);
  }
}

// ---------------- heads ----------------
__global__ __launch_bounds__(256) void k_heads(const float* __restrict__ f,
        const float* __restrict__ Wm1, const float* __restrict__ bm1,
        const float* __restrict__ Wm2, const float* __restrict__ bm2,
        const float* __restrict__ Wd1, const float* __restrict__ bd1,
        const float* __restrict__ Wd2, const float* __restrict__ bd2,
        float* __restrict__ out){
  __shared__ float swm1[64*32];
  __shared__ float swm2[32*4];
  __shared__ float swd1[64*16];
  __shared__ float swd2[16*4];
  __shared__ float sbm1[32], sbm2[4], sbd1[16], sbd2[4];
  int tid = threadIdx.x;
  for (int i = tid; i < 2048; i += 256) swm1[i] = Wm1[i];
  for (int i = tid; i < 1024; i += 256) swd1[i] = Wd1[i];
  if (tid < 128) swm2[tid] = Wm2[tid];
  if (tid < 64) swd2[tid] = Wd2[tid];
  if (tid < 32) sbm1[tid] = bm1[tid];
  if (tid < 16) sbd1[tid] = bd1[tid];
  if (tid < 4){ sbm2[tid] = bm2[tid]; sbd2[tid] = bd2[tid]; }
  __syncthreads();
  int n = blockIdx.x*256 + tid;
  if (n >= NN) return;
  float fr[64];
  const float4* f4 = (const float4*)(f + (size_t)n*64);
  #pragma unroll
  for (int i = 0; i < 16; ++i){ float4 v = f4[i]; fr[i*4]=v.x; fr[i*4+1]=v.y; fr[i*4+2]=v.z; fr[i*4+3]=v.w; }
  // magnitude head
  float m1[32];
  #pragma unroll
  for (int c2 = 0; c2 < 32; ++c2) m1[c2] = sbm1[c2];
  for (int k = 0; k < 64; ++k){
    float fv = fr[k];
    #pragma unroll
    for (int c2 = 0; c2 < 32; ++c2) m1[c2] += fv*swm1[k*32+c2];
  }
  #pragma unroll
  for (int c2 = 0; c2 < 32; ++c2) m1[c2] = leaky01(m1[c2]);
  float mo[4];
  #pragma unroll
  for (int o = 0; o < 4; ++o) mo[o] = sbm2[o];
  for (int c2 = 0; c2 < 32; ++c2){
    float mv = m1[c2];
    #pragma unroll
    for (int o = 0; o < 4; ++o) mo[o] += mv*swm2[c2*4+o];
  }
  // direction head
  float d1[16];
  #pragma unroll
  for (int c2 = 0; c2 < 16; ++c2) d1[c2] = sbd1[c2];
  for (int k = 0; k < 64; ++k){
    float fv = fr[k];
    #pragma unroll
    for (int c2 = 0; c2 < 16; ++c2) d1[c2] += fv*swd1[k*16+c2];
  }
  #pragma unroll
  for (int c2 = 0; c2 < 16; ++c2) d1[c2] = fmaxf(d1[c2], 0.f);
  float dv[4];
  #pragma unroll
  for (int o = 0; o < 4; ++o) dv[o] = sbd2[o];
  for (int c2 = 0; c2 < 16; ++c2){
    float xv = d1[c2];
    #pragma unroll
    for (int o = 0; o < 4; ++o) dv[o] += xv*swd2[c2*4+o];
  }
  float4* o4 = (float4*)out;
  o4[n] = make_float4(fmaxf(mo[0],0.f)+1e-4f, fmaxf(mo[1],0.f)+1e-4f,
                      fmaxf(mo[2],0.f)+1e-4f, fmaxf(mo[3],0.f)+1e-4f);
  o4[NN + n] = make_float4(dv[0], dv[1], dv[2], dv[3]);
}

extern "C" void kernel_launch(void* const* d_in, const int* in_sizes, int n_in,
                              void* d_out, int out_size, void* d_ws, size_t ws_size,
                              hipStream_t stream){
  const float* x    = (const float*)d_in[0];
  const int*   eidx = (const int*)d_in[1];
  const float* ew   = (const float*)d_in[2];
  const float* Wg1  = (const float*)d_in[3];
  const float* bg1  = (const float*)d_in[4];
  const float* Wg2  = (const float*)d_in[5];
  const float* bg2  = (const float*)d_in[6];
  const float* lng  = (const float*)d_in[7];
  const float* lnb  = (const float*)d_in[8];
  const float* Wih0 = (const float*)d_in[9];
  const float* Whh0 = (const float*)d_in[10];
  const float* bih0 = (const float*)d_in[11];
  const float* bhh0 = (const float*)d_in[12];
  const float* Wih1 = (const float*)d_in[13];
  const float* Whh1 = (const float*)d_in[14];
  const float* bih1 = (const float*)d_in[15];
  const float* bhh1 = (const float*)d_in[16];
  const float* Wm1  = (const float*)d_in[17];
  const float* bm1  = (const float*)d_in[18];
  const float* Wm2  = (const float*)d_in[19];
  const float* bm2  = (const float*)d_in[20];
  const float* Wd1  = (const float*)d_in[21];
  const float* bd1  = (const float*)d_in[22];
  const float* Wd2  = (const float*)d_in[23];
  const float* bd2  = (const float*)d_in[24];
  const int* src = eidx;
  const int* dst = eidx + EE;
  float* out = (float*)d_out;

  char* p = (char*)d_ws;
  auto alloc = [&](size_t bytes)->char*{ char* r = p; p += (bytes + 255) & ~(size_t)255; return r; };
  float* deg    = (float*)alloc((size_t)NN*4);        // becomes dinv
  float* enorm  = (float*)alloc((size_t)EE*4);
  int*   counts = (int*)  alloc((size_t)NN*4);
  int*   rowptr = (int*)  alloc((size_t)(NN+1)*4);
  int*   cursor = (int*)  alloc((size_t)NN*4);
  int*   colsrc = (int*)  alloc((size_t)EE*4);
  float* AX     = (float*)alloc((size_t)NN*49*4);
  float* H1     = (float*)alloc((size_t)NN*64*4);
  float* Z2     = (float*)alloc((size_t)NN*64*4);
  float* XT     = (float*)alloc((size_t)NN*64*4);
  float* ST     = (float*)alloc((size_t)4*NN*64*4);   // h0,c0,h1,c1
  uint4* WB     = (uint4*)alloc((size_t)2*4096*16);
  float* BS     = (float*)alloc((size_t)2*256*4);
  float* h0 = ST;
  float* c0 = ST + (size_t)NN*64;
  float* h1s= ST + (size_t)2*NN*64;
  float* c1 = ST + (size_t)3*NN*64;

  hipMemsetAsync(counts, 0, (size_t)NN*4, stream);
  k_init_deg<<<(NN+255)/256, 256, 0, stream>>>(deg);
  k_edge_count<<<(EE+255)/256, 256, 0, stream>>>(src, dst, ew, deg, counts);
  k_dinv<<<(NN+255)/256, 256, 0, stream>>>(deg);
  k_scan<<<1, 1024, 0, stream>>>(counts, rowptr, cursor);
  k_scatter<<<(EE+255)/256, 256, 0, stream>>>(src, dst, ew, deg, cursor, colsrc, enorm);
  k_prep_lstm<<<(2*4096+255)/256, 256, 0, stream>>>(Wih0, Whh0, Wih1, Whh1, WB);
  k_prep_bias<<<2, 256, 0, stream>>>(bih0, bhh0, bih1, bhh1, BS);
  k_agg_x<<<NN/4, 256, 0, stream>>>(x, deg, rowptr, colsrc, enorm, AX);
  hipMemsetAsync(ST, 0, (size_t)4*NN*64*4, stream);

  for (int t = 0; t < TT; ++t){
    k_y1<<<NN/4, 256, 0, stream>>>(AX, Wg1, bg1, H1, t);
    k_z2<<<NN/16, 256, 0, stream>>>(H1, Wg2, Z2);
    k_agg_ln<<<NN/4, 256, 0, stream>>>(Z2, deg, rowptr, colsrc, enorm, bg2, lng, lnb, XT);
    k_lstm<<<NN/16, 256, 0, stream>>>(XT, h0, c0, WB, BS);
    k_lstm<<<NN/16, 256, 0, stream>>>(h0, h1s, c1, WB + 4096, BS + 256);
  }
  k_heads<<<(NN+255)/256, 256, 0, stream>>>(h1s, Wm1, bm1, Wm2, bm2, Wd1, bd1, Wd2, bd2, out);
}

// Round 2
// 1033.265 us; speedup vs baseline: 1.8216x; 1.8216x over previous
//
#include <hip/hip_runtime.h>
#include <stdint.h>

#define NN 50000
#define NP 50048          // padded to 64 for the MFMA LSTM kernel
#define EE 400000
#define TT 7
#define LN_EPS 1e-5f

typedef __attribute__((ext_vector_type(8))) short bf16x8;
typedef __attribute__((ext_vector_type(4))) float f32x4;

__device__ __forceinline__ float leaky01(float x){ return x > 0.f ? x : 0.01f*x; }
__device__ __forceinline__ float sigmoidf(float x){ return 1.f/(1.f+__expf(-x)); }
__device__ __forceinline__ float tanhfast(float x){ float e=__expf(2.f*x); return 1.f - 2.f/(e+1.f); }
__device__ __forceinline__ unsigned bf16rne(float f){
  unsigned u = __float_as_uint(f);
  return (u + 0x7fffu + ((u>>16)&1u)) >> 16;
}
__device__ __forceinline__ float blo(unsigned u){ return __uint_as_float(u<<16); }
__device__ __forceinline__ float bhi(unsigned u){ return __uint_as_float(u & 0xffff0000u); }

// ---------------- graph norm / CSR build ----------------
__global__ void k_init_deg(float* deg){
  int i = blockIdx.x*blockDim.x + threadIdx.x;
  if (i < NN) deg[i] = 1.0f;                // self-loop weight
}
__global__ void k_edge_count(const int* __restrict__ src, const int* __restrict__ dst,
                             const float* __restrict__ ew, float* deg, int* counts){
  int e = blockIdx.x*blockDim.x + threadIdx.x;
  if (e < EE){
    int d = dst[e];
    atomicAdd(&deg[d], ew[e]);
    atomicAdd(&counts[d], 1);
  }
}
__global__ void k_dinv(float* deg){
  int i = blockIdx.x*blockDim.x + threadIdx.x;
  if (i < NN) deg[i] = rsqrtf(deg[i]);      // deg >= 1 always
}
// single-block inclusive scan over counts -> rowptr/cursor
__global__ void k_scan(const int* __restrict__ counts, int* rowptr, int* cursor){
  __shared__ int sb[2][1024];
  int tid = threadIdx.x;
  int carry = 0;
  for (int base = 0; base < NN; base += 1024){
    int i = base + tid;
    int v = (i < NN) ? counts[i] : 0;
    int cur = 0;
    sb[0][tid] = v;
    __syncthreads();
    for (int off = 1; off < 1024; off <<= 1){
      int val = sb[cur][tid];
      if (tid >= off) val += sb[cur][tid - off];
      sb[cur^1][tid] = val;
      cur ^= 1;
      __syncthreads();
    }
    int incl = sb[cur][tid];
    if (i < NN){ rowptr[i+1] = carry + incl; cursor[i] = carry + incl - v; }
    int tot = sb[cur][1023];
    __syncthreads();
    carry += tot;
  }
  if (tid == 0) rowptr[0] = 0;
}
__global__ void k_scatter(const int* __restrict__ src, const int* __restrict__ dst,
                          const float* __restrict__ ew, const float* __restrict__ dinv,
                          int* cursor, int* colsrc, float* enorm){
  int e = blockIdx.x*blockDim.x + threadIdx.x;
  if (e < EE){
    int s = src[e], d = dst[e];
    float nv = dinv[s]*ew[e]*dinv[d];
    int slot = atomicAdd(&cursor[d], 1);
    colsrc[slot] = s;
    enorm[slot] = nv;
  }
}

// ---------------- LSTM weight packing (B-fragment order) ----------------
// WF entry ((ct*2+s)*2+which)*64 + lane  holds 8 bf16:
//   W[16*ct + (lane&15)][32*s + (lane>>4)*8 + j], j=0..7  (W row-major [256][64])
// which: 0 = Wih, 1 = Whh. Per layer: 4096 uint4 = 64 KB.
__global__ void k_prep_wf(const float* __restrict__ Wih0, const float* __restrict__ Whh0,
                          const float* __restrict__ Wih1, const float* __restrict__ Whh1,
                          uint4* WF){
  int idx = blockIdx.x*blockDim.x + threadIdx.x;
  if (idx >= 8192) return;
  int L = idx >> 12;
  int r = idx & 4095;
  int lane = r & 63;
  int e = r >> 6;
  int which = e & 1;
  int cs = e >> 1;
  int s = cs & 1, ct = cs >> 1;
  int row = ct*16 + (lane & 15);
  int kb = s*32 + (lane >> 4)*8;
  const float* W = L ? (which ? Whh1 : Wih1) : (which ? Whh0 : Wih0);
  const float* p = W + row*64 + kb;
  uint4 v;
  v.x = bf16rne(p[0]) | (bf16rne(p[1])<<16);
  v.y = bf16rne(p[2]) | (bf16rne(p[3])<<16);
  v.z = bf16rne(p[4]) | (bf16rne(p[5])<<16);
  v.w = bf16rne(p[6]) | (bf16rne(p[7])<<16);
  WF[idx] = v;
}
__global__ void k_prep_bias(const float* bih0, const float* bhh0,
                            const float* bih1, const float* bhh1, float* BS){
  int j = threadIdx.x; int L = blockIdx.x;
  if (j < 256) BS[L*256+j] = L ? (bih1[j]+bhh1[j]) : (bih0[j]+bhh0[j]);
}

// ---------------- GCN ----------------
// AX[i][0..48] = sum over in-edges (+self) of norm * x[src][0..48]; one wave per node
__global__ __launch_bounds__(256) void k_agg_x(const float* __restrict__ x,
        const float* __restrict__ dinv, const int* __restrict__ rowptr,
        const int* __restrict__ colsrc, const float* __restrict__ enorm,
        float* __restrict__ AX){
  int lane = threadIdx.x & 63, w = threadIdx.x >> 6;
  int i = blockIdx.x*4 + w;
  int beg = rowptr[i], end = rowptr[i+1];
  float di = dinv[i];
  float acc = 0.f;
  if (lane < 49) acc = di*di*x[(size_t)i*49 + lane];
  for (int s = beg; s < end; ++s){
    int cs = colsrc[s]; float wv = enorm[s];
    if (lane < 49) acc += wv * x[(size_t)cs*49 + lane];
  }
  if (lane < 49) AX[(size_t)i*49 + lane] = acc;
}
// Fused: H1 = leaky(AX_t @ Wg1 + bg1); Z2 = H1 @ Wg2.  16 nodes/block.
__global__ __launch_bounds__(256) void k_gcn2(const float* __restrict__ AX,
        const float* __restrict__ Wg1, const float* __restrict__ bg1,
        const float* __restrict__ Wg2, float* __restrict__ Z2, int t){
  __shared__ float sw1[7*64];
  __shared__ float sb1[64];
  __shared__ float sw2[64*64];
  __shared__ float sax[16*8];
  __shared__ __align__(16) float sr[16*64];
  int tid = threadIdx.x;
  const float4* w4 = (const float4*)Wg2;
  float4* sw4 = (float4*)sw2;
  #pragma unroll
  for (int i = 0; i < 4; ++i) sw4[tid + i*256] = w4[tid + i*256];
  for (int i = tid; i < 448; i += 256) sw1[i] = Wg1[i];
  if (tid < 64) sb1[tid] = bg1[tid];
  int base = blockIdx.x*16;
  if (tid < 112){
    int n = tid / 7, k = tid % 7;
    sax[n*8 + k] = AX[(size_t)(base+n)*49 + t*7 + k];
  }
  __syncthreads();
  // H1 into sr: 1024 outputs, 4 per thread
  #pragma unroll
  for (int i = 0; i < 4; ++i){
    int idx = i*256 + tid;
    int n = idx >> 6, c = idx & 63;
    float acc = sb1[c];
    #pragma unroll
    for (int k = 0; k < 7; ++k) acc += sax[n*8+k]*sw1[k*64+c];
    sr[idx] = leaky01(acc);
  }
  __syncthreads();
  int c = tid & 63, w = tid >> 6;
  float a0=0.f, a1=0.f, a2=0.f, a3=0.f;
  const float* r = sr + w*256;
  for (int k = 0; k < 64; ++k){
    float wv = sw2[k*64+c];
    a0 += r[k]*wv; a1 += r[64+k]*wv; a2 += r[128+k]*wv; a3 += r[192+k]*wv;
  }
  size_t o = (size_t)(base + w*4)*64 + c;
  Z2[o] = a0; Z2[o+64] = a1; Z2[o+128] = a2; Z2[o+192] = a3;
}
// XT(bf16) = LN(leaky(A@Z2 + bg2)) ; one wave per node, lane = feature
__global__ __launch_bounds__(256) void k_agg_ln(const float* __restrict__ Z2,
        const float* __restrict__ dinv, const int* __restrict__ rowptr,
        const int* __restrict__ colsrc, const float* __restrict__ enorm,
        const float* __restrict__ bg2, const float* __restrict__ lng,
        const float* __restrict__ lnb, ushort* __restrict__ XT){
  int lane = threadIdx.x & 63, w = threadIdx.x >> 6;
  int i = blockIdx.x*4 + w;
  int beg = rowptr[i], end = rowptr[i+1];
  float di = dinv[i];
  float acc = di*di*Z2[(size_t)i*64 + lane];
  for (int s = beg; s < end; ++s){
    acc += enorm[s]*Z2[(size_t)colsrc[s]*64 + lane];
  }
  acc += bg2[lane];
  acc = leaky01(acc);
  float sum = acc;
  #pragma unroll
  for (int off = 32; off >= 1; off >>= 1) sum += __shfl_xor(sum, off, 64);
  float mu = sum * (1.f/64.f);
  float d = acc - mu;
  float vs = d*d;
  #pragma unroll
  for (int off = 32; off >= 1; off >>= 1) vs += __shfl_xor(vs, off, 64);
  float rs = rsqrtf(vs*(1.f/64.f) + LN_EPS);
  XT[(size_t)i*64+lane] = (ushort)bf16rne(d*rs*lng[lane] + lnb[lane]);
}

// ---------------- LSTM step via MFMA ----------------
// 2 waves/block; each wave: 32 nodes (2 m-tiles of 16), all 256 gate columns.
// acc tile ct covers gate cols [16ct,16ct+16); lane holds (rows quad*4+r, col lane&15).
// For unit u=16cp+col: i=acc[cp], f=acc[cp+4], g=acc[cp+8], o=acc[cp+12] -> all in-lane.
__global__ __launch_bounds__(128) void k_lstm_mfma(
    const ushort* __restrict__ xin,   // [NP][64] bf16
    ushort* __restrict__ h,           // [NP][64] bf16, in/out
    float* __restrict__ c,            // [NP][64] f32, in/out
    const uint4* __restrict__ WF,     // 4096 frag-packed uint4 (64 KB, L2-hot)
    const float* __restrict__ BS){    // 256 fused bias
  int lane = threadIdx.x & 63;
  int wave = threadIdx.x >> 6;
  int base = blockIdx.x*64 + wave*32;
  int col = lane & 15, quad = lane >> 4;
  bf16x8 ax[2][2], ah[2][2];
  #pragma unroll
  for (int mt = 0; mt < 2; ++mt)
    #pragma unroll
    for (int s = 0; s < 2; ++s){
      int addr = (base + mt*16 + col)*64 + s*32 + quad*8;
      ax[mt][s] = *(const bf16x8*)(xin + addr);
      ah[mt][s] = *(const bf16x8*)(h + addr);
    }
  f32x4 acc[2][16];
  #pragma unroll
  for (int ct = 0; ct < 16; ++ct){
    float b = BS[ct*16 + col];
    acc[0][ct] = (f32x4){b,b,b,b};
    acc[1][ct] = (f32x4){b,b,b,b};
  }
  #pragma unroll
  for (int ct = 0; ct < 16; ++ct){
    #pragma unroll
    for (int s = 0; s < 2; ++s){
      uint4 wi = WF[((ct*2+s)*2+0)*64 + lane];
      uint4 wh = WF[((ct*2+s)*2+1)*64 + lane];
      bf16x8 bwi = *(bf16x8*)&wi;
      bf16x8 bwh = *(bf16x8*)&wh;
      #pragma unroll
      for (int mt = 0; mt < 2; ++mt){
        acc[mt][ct] = __builtin_amdgcn_mfma_f32_16x16x32_bf16(ax[mt][s], bwi, acc[mt][ct], 0,0,0);
        acc[mt][ct] = __builtin_amdgcn_mfma_f32_16x16x32_bf16(ah[mt][s], bwh, acc[mt][ct], 0,0,0);
      }
    }
  }
  #pragma unroll
  for (int mt = 0; mt < 2; ++mt){
    #pragma unroll
    for (int cp = 0; cp < 4; ++cp){
      #pragma unroll
      for (int r = 0; r < 4; ++r){
        int node = base + mt*16 + quad*4 + r;
        int idx = node*64 + cp*16 + col;
        float ig = sigmoidf(acc[mt][cp][r]);
        float fg = sigmoidf(acc[mt][cp+4][r]);
        float gg = tanhfast(acc[mt][cp+8][r]);
        float og = sigmoidf(acc[mt][cp+12][r]);
        float cn = fg*c[idx] + ig*gg;
        c[idx] = cn;
        h[idx] = (ushort)bf16rne(og*tanhfast(cn));
      }
    }
  }
}

// ---------------- heads ----------------
__global__ __launch_bounds__(256) void k_heads(const ushort* __restrict__ f,
        const float* __restrict__ Wm1, const float* __restrict__ bm1,
        const float* __restrict__ Wm2, const float* __restrict__ bm2,
        const float* __restrict__ Wd1, const float* __restrict__ bd1,
        const float* __restrict__ Wd2, const float* __restrict__ bd2,
        float* __restrict__ out){
  __shared__ float swm1[64*32];
  __shared__ float swm2[32*4];
  __shared__ float swd1[64*16];
  __shared__ float swd2[16*4];
  __shared__ float sbm1[32], sbm2[4], sbd1[16], sbd2[4];
  int tid = threadIdx.x;
  for (int i = tid; i < 2048; i += 256) swm1[i] = Wm1[i];
  for (int i = tid; i < 1024; i += 256) swd1[i] = Wd1[i];
  if (tid < 128) swm2[tid] = Wm2[tid];
  if (tid < 64) swd2[tid] = Wd2[tid];
  if (tid < 32) sbm1[tid] = bm1[tid];
  if (tid < 16) sbd1[tid] = bd1[tid];
  if (tid < 4){ sbm2[tid] = bm2[tid]; sbd2[tid] = bd2[tid]; }
  __syncthreads();
  int n = blockIdx.x*256 + tid;
  if (n >= NN) return;
  float fr[64];
  const uint* f2 = (const uint*)(f + (size_t)n*64);
  #pragma unroll
  for (int i = 0; i < 32; ++i){ uint u = f2[i]; fr[2*i] = blo(u); fr[2*i+1] = bhi(u); }
  float m1[32];
  #pragma unroll
  for (int c2 = 0; c2 < 32; ++c2) m1[c2] = sbm1[c2];
  for (int k = 0; k < 64; ++k){
    float fv = fr[k];
    #pragma unroll
    for (int c2 = 0; c2 < 32; ++c2) m1[c2] += fv*swm1[k*32+c2];
  }
  #pragma unroll
  for (int c2 = 0; c2 < 32; ++c2) m1[c2] = leaky01(m1[c2]);
  float mo[4];
  #pragma unroll
  for (int o = 0; o < 4; ++o) mo[o] = sbm2[o];
  for (int c2 = 0; c2 < 32; ++c2){
    float mv = m1[c2];
    #pragma unroll
    for (int o = 0; o < 4; ++o) mo[o] += mv*swm2[c2*4+o];
  }
  float d1[16];
  #pragma unroll
  for (int c2 = 0; c2 < 16; ++c2) d1[c2] = sbd1[c2];
  for (int k = 0; k < 64; ++k){
    float fv = fr[k];
    #pragma unroll
    for (int c2 = 0; c2 < 16; ++c2) d1[c2] += fv*swd1[k*16+c2];
  }
  #pragma unroll
  for (int c2 = 0; c2 < 16; ++c2) d1[c2] = fmaxf(d1[c2], 0.f);
  float dv[4];
  #pragma unroll
  for (int o = 0; o < 4; ++o) dv[o] = sbd2[o];
  for (int c2 = 0; c2 < 16; ++c2){
    float xv = d1[c2];
    #pragma unroll
    for (int o = 0; o < 4; ++o) dv[o] += xv*swd2[c2*4+o];
  }
  float4* o4 = (float4*)out;
  o4[n] = make_float4(fmaxf(mo[0],0.f)+1e-4f, fmaxf(mo[1],0.f)+1e-4f,
                      fmaxf(mo[2],0.f)+1e-4f, fmaxf(mo[3],0.f)+1e-4f);
  o4[NN + n] = make_float4(dv[0], dv[1], dv[2], dv[3]);
}

extern "C" void kernel_launch(void* const* d_in, const int* in_sizes, int n_in,
                              void* d_out, int out_size, void* d_ws, size_t ws_size,
                              hipStream_t stream){
  const float* x    = (const float*)d_in[0];
  const int*   eidx = (const int*)d_in[1];
  const float* ew   = (const float*)d_in[2];
  const float* Wg1  = (const float*)d_in[3];
  const float* bg1  = (const float*)d_in[4];
  const float* Wg2  = (const float*)d_in[5];
  const float* bg2  = (const float*)d_in[6];
  const float* lng  = (const float*)d_in[7];
  const float* lnb  = (const float*)d_in[8];
  const float* Wih0 = (const float*)d_in[9];
  const float* Whh0 = (const float*)d_in[10];
  const float* bih0 = (const float*)d_in[11];
  const float* bhh0 = (const float*)d_in[12];
  const float* Wih1 = (const float*)d_in[13];
  const float* Whh1 = (const float*)d_in[14];
  const float* bih1 = (const float*)d_in[15];
  const float* bhh1 = (const float*)d_in[16];
  const float* Wm1  = (const float*)d_in[17];
  const float* bm1  = (const float*)d_in[18];
  const float* Wm2  = (const float*)d_in[19];
  const float* bm2  = (const float*)d_in[20];
  const float* Wd1  = (const float*)d_in[21];
  const float* bd1  = (const float*)d_in[22];
  const float* Wd2  = (const float*)d_in[23];
  const float* bd2  = (const float*)d_in[24];
  const int* src = eidx;
  const int* dst = eidx + EE;
  float* out = (float*)d_out;

  char* p = (char*)d_ws;
  auto alloc = [&](size_t bytes)->char*{ char* r = p; p += (bytes + 255) & ~(size_t)255; return r; };
  float*  deg    = (float*)alloc((size_t)NN*4);        // becomes dinv
  float*  enorm  = (float*)alloc((size_t)EE*4);
  int*    counts = (int*)  alloc((size_t)NN*4);
  int*    rowptr = (int*)  alloc((size_t)(NN+1)*4);
  int*    cursor = (int*)  alloc((size_t)NN*4);
  int*    colsrc = (int*)  alloc((size_t)EE*4);
  float*  AX     = (float*)alloc((size_t)NN*49*4);
  float*  Z2     = (float*)alloc((size_t)NN*64*4);
  ushort* XTb    = (ushort*)alloc((size_t)NP*64*2);
  char*   ST     = alloc((size_t)NP*64*12);            // h0b,h1b (bf16) + c0,c1 (f32)
  uint4*  WF     = (uint4*)alloc((size_t)2*4096*16);
  float*  BS     = (float*)alloc((size_t)2*256*4);
  ushort* h0b = (ushort*)ST;
  ushort* h1b = (ushort*)(ST + (size_t)NP*64*2);
  float*  c0  = (float*)(ST + (size_t)NP*64*4);
  float*  c1  = (float*)(ST + (size_t)NP*64*8);

  hipMemsetAsync(counts, 0, (size_t)NN*4, stream);
  k_init_deg<<<(NN+255)/256, 256, 0, stream>>>(deg);
  k_edge_count<<<(EE+255)/256, 256, 0, stream>>>(src, dst, ew, deg, counts);
  k_dinv<<<(NN+255)/256, 256, 0, stream>>>(deg);
  k_scan<<<1, 1024, 0, stream>>>(counts, rowptr, cursor);
  k_scatter<<<(EE+255)/256, 256, 0, stream>>>(src, dst, ew, deg, cursor, colsrc, enorm);
  k_prep_wf<<<32, 256, 0, stream>>>(Wih0, Whh0, Wih1, Whh1, WF);
  k_prep_bias<<<2, 256, 0, stream>>>(bih0, bhh0, bih1, bhh1, BS);
  k_agg_x<<<NN/4, 256, 0, stream>>>(x, deg, rowptr, colsrc, enorm, AX);
  hipMemsetAsync(ST, 0, (size_t)NP*64*12, stream);     // zero h0,h1,c0,c1

  for (int t = 0; t < TT; ++t){
    k_gcn2<<<NN/16, 256, 0, stream>>>(AX, Wg1, bg1, Wg2, Z2, t);
    k_agg_ln<<<NN/4, 256, 0, stream>>>(Z2, deg, rowptr, colsrc, enorm, bg2, lng, lnb, XTb);
    k_lstm_mfma<<<NP/64, 128, 0, stream>>>(XTb, h0b, c0, WF, BS);
    k_lstm_mfma<<<NP/64, 128, 0, stream>>>(h0b, h1b, c1, WF + 4096, BS + 256);
  }
  k_heads<<<(NN+255)/256, 256, 0, stream>>>(h1b, Wm1, bm1, Wm2, bm2, Wd1, bd1, Wd2, bd2, out);
}